// Round 4
// baseline (637.275 us; speedup 1.0000x reference)
//
#include <hip/hip_runtime.h>
#include <stdint.h>
#include <stddef.h>

typedef unsigned short u16;
typedef __attribute__((ext_vector_type(8))) short short8;
typedef __attribute__((ext_vector_type(4))) float f32x4;

#define DEVI __device__ __forceinline__

DEVI u16 f2bf(float f) {
  union { float f; unsigned u; } c; c.f = f;
  unsigned r = c.u + 0x7fff + ((c.u >> 16) & 1);
  return (u16)(r >> 16);
}

// ---------------------------------------------------------------------------
// LDS layout per 128x64 tile: row*64 bf16; 16B granule g of row r at slot
// g^(r&7) (XOR swizzle -> fragment ds_read_b128 aliases only 2-way = free).
// ---------------------------------------------------------------------------
DEVI void mfma_phase(const u16* As, const u16* Bs, f32x4 acc[4][4])
{
  const int lane = threadIdx.x & 63;
  const int w    = threadIdx.x >> 6;
  const int l16  = lane & 15, lq = lane >> 4;
  const int wm   = (w >> 1) * 64, wn = (w & 1) * 64;
#pragma unroll
  for (int kc = 0; kc < 2; kc++) {
    short8 afr[4], bfr[4];
#pragma unroll
    for (int rt = 0; rt < 4; rt++) {
      int m  = wm + rt * 16 + l16;
      int gr = (kc * 4 + lq) ^ (m & 7);
      afr[rt] = *(const short8*)(As + m * 64 + gr * 8);
    }
#pragma unroll
    for (int ct = 0; ct < 4; ct++) {
      int n  = wn + ct * 16 + l16;
      int gr = (kc * 4 + lq) ^ (n & 7);
      bfr[ct] = *(const short8*)(Bs + n * 64 + gr * 8);
    }
#pragma unroll
    for (int rt = 0; rt < 4; rt++)
#pragma unroll
      for (int ct = 0; ct < 4; ct++)
        acc[rt][ct] = __builtin_amdgcn_mfma_f32_16x16x32_bf16(afr[rt], bfr[ct], acc[rt][ct], 0, 0, 0);
  }
}

// pack 8 fp32 -> 8 bf16
DEVI short8 pack8(f32x4 a, f32x4 b) {
  short8 v;
#pragma unroll
  for (int i = 0; i < 4; i++) { v[i] = (short)f2bf(a[i]); v[i + 4] = (short)f2bf(b[i]); }
  return v;
}

// stage 128 rows x 64 K-elems of fp32 row-major [*, ldr] -> bf16 LDS
DEVI void stage_A(const float* A, int ldr, int k0, u16* dst)
{
  const int t = threadIdx.x;
  const int g = t & 7, rb = t >> 3;   // rb 0..31
#pragma unroll
  for (int p = 0; p < 4; p++) {
    int row = p * 32 + rb;
    const float* src = A + (size_t)row * ldr + k0 + g * 8;
    f32x4 a = *(const f32x4*)src;
    f32x4 b = *(const f32x4*)(src + 4);
    *(short8*)(dst + row * 64 + (g ^ (row & 7)) * 8) = pack8(a, b);
  }
}

// ---------------------------------------------------------------------------
// acc += A[128,K] * B'[128,K]^T  (A tile-base pre-offset; fp32 global data)
// MODE 0: B0 row-major [*,K].  MODE 1: fused (B0+B1) row-major [*,K].
// MODE 2: Bw scattered in d_out (fp32): elem (row,k) at
//         B0[row*4096 + (k>>7)*512 + (k&127)]   (B0 pre-offset by obase+bn*128)
// ---------------------------------------------------------------------------
template <int MODE>
DEVI void gemm_term(const float* A, const float* B0, const float* B1, int K,
                    u16* As, u16* Bs, f32x4 acc[4][4])
{
  const int t = threadIdx.x;
  const int g = t & 7, rb = t >> 3;

  for (int k0 = 0; k0 < K; k0 += 64) {
    stage_A(A, K, k0, As);
#pragma unroll
    for (int p = 0; p < 4; p++) {
      int row = p * 32 + rb;
      const float* src;
      if (MODE == 2) src = B0 + (size_t)row * 4096 + (k0 >> 7) * 512 + (k0 & 127) + g * 8;
      else           src = B0 + (size_t)row * K + k0 + g * 8;
      f32x4 a = *(const f32x4*)src;
      f32x4 b = *(const f32x4*)(src + 4);
      if (MODE == 1) {
        const float* s2 = B1 + (size_t)row * K + k0 + g * 8;
        f32x4 c = *(const f32x4*)s2;
        f32x4 d = *(const f32x4*)(s2 + 4);
        a = a + c; b = b + d;   // fp32 add BEFORE bf16 rounding
      }
      *(short8*)(Bs + row * 64 + (g ^ (row & 7)) * 8) = pack8(a, b);
    }
    __syncthreads();
    mfma_phase(As, Bs, acc);
    __syncthreads();
  }
}

// NN term for k_bw: acc += A[128,K] * B[K, colblock of 128] (B fp32 [K,512])
DEVI void nn_term(const float* A, const float* B, int K, u16* As, u16* Bs, f32x4 acc[4][4])
{
  const int t  = threadIdx.x;
  const int ks = t >> 4;   // 0..15
  const int ng = t & 15;   // n-granule of 8

  for (int k0 = 0; k0 < K; k0 += 64) {
    stage_A(A, K, k0, As);
#pragma unroll
    for (int i = 0; i < 4; i++) {
      int kloc = i * 16 + ks;
      const float* src = B + (size_t)(k0 + kloc) * 512 + ng * 8;
      f32x4 a = *(const f32x4*)src;
      f32x4 b = *(const f32x4*)(src + 4);
#pragma unroll
      for (int e = 0; e < 8; e++) {
        int nloc = ng * 8 + e;
        float val = (e < 4) ? a[e] : b[e - 4];
        Bs[nloc * 64 + ((kloc >> 3) ^ (nloc & 7)) * 8 + (kloc & 7)] = f2bf(val);
      }
    }
    __syncthreads();
    mfma_phase(As, Bs, acc);
    __syncthreads();
  }
}

DEVI void zero_acc(f32x4 acc[4][4]) {
  f32x4 z = {0.f, 0.f, 0.f, 0.f};
#pragma unroll
  for (int a = 0; a < 4; a++)
#pragma unroll
    for (int b = 0; b < 4; b++) acc[a][b] = z;
}

struct Params {
  const float *x_input, *y_target, *j1, *v1, *s1, *x1, *j2, *v2, *s2, *x2;
  const float *W0, *W1, *W2, *V0, *V1, *V2, *Eg0, *Eg1, *Ed1, *Ed2;
};

// ---------------------------------------------------------------------------
// k_bw: Bw1n = -(Eg0@W0 + Ed1@V1), Bw2n = -(Eg1@W1 + Ed2@V2)  [512,512] each,
// stored FP32, scattered into d_out rows 0..127:
//   Bw[n][k] -> out[(n&127)*4096 + obase + (n>>7)*128 + (k>>7)*512 + (k&127)]
// (cells are overwritten with final outputs by the fix pass afterwards)
// ---------------------------------------------------------------------------
__global__ __launch_bounds__(256) void k_bw(Params P, float* __restrict__ out)
{
  __shared__ u16 As[128 * 64];
  __shared__ u16 Bs[128 * 64];
  int b   = blockIdx.x;
  int mat = b >> 4;
  int loc = b & 15;
  int bmw = loc >> 2;   // n>>7
  int bnw = loc & 3;    // k>>7

  f32x4 acc[4][4];
  zero_acc(acc);
  int obase;
  if (mat == 0) {
    nn_term(P.Eg0 + (size_t)bmw * 128 * 1024, P.W0 + bnw * 128, 1024, As, Bs, acc);
    nn_term(P.Ed1 + (size_t)bmw * 128 * 512,  P.V1 + bnw * 128,  512, As, Bs, acc);
    obase = 0;
  } else {
    nn_term(P.Eg1 + (size_t)bmw * 128 * 512,  P.W1 + bnw * 128,  512, As, Bs, acc);
    nn_term(P.Ed2 + (size_t)bmw * 128 * 256,  P.V2 + bnw * 128,  256, As, Bs, acc);
    obase = 2048;
  }

  const int lane = threadIdx.x & 63;
  const int w    = threadIdx.x >> 6;
  const int l16  = lane & 15, lq = lane >> 4;
  const int wm   = (w >> 1) * 64, wn = (w & 1) * 64;
#pragma unroll
  for (int rt = 0; rt < 4; rt++)
#pragma unroll
    for (int ct = 0; ct < 4; ct++)
#pragma unroll
      for (int i = 0; i < 4; i++) {
        int rl = wm + rt * 16 + lq * 4 + i;   // n & 127
        int cl = wn + ct * 16 + l16;          // k & 127
        out[(size_t)rl * 4096 + obase + bmw * 128 + bnw * 512 + cl] = -acc[rt][ct][i];
      }
}

// ---------------------------------------------------------------------------
// k_main: per layer total = 4 GEMM terms - 2*x, then fused LIF (all fp32).
// fix==0: bm 1..63 (bm==0 exits).  fix==1: bm==0 only (8 blocks; each block's
// Bw reads are exactly its own later writes -> self-ordered, race-free).
// ---------------------------------------------------------------------------
__global__ __launch_bounds__(256) void k_main(Params P, float* __restrict__ out, int fix)
{
  __shared__ u16 As[128 * 64];
  __shared__ u16 Bs[128 * 64];
  int job, bm, bn;
  if (fix) {
    job = blockIdx.x >> 2; bn = blockIdx.x & 3; bm = 0;
  } else {
    job = blockIdx.x >> 8;
    int local = blockIdx.x & 255;
    bm = local & 63; bn = local >> 6;
    if (bm == 0) return;
  }

  f32x4 acc[4][4];
  zero_acc(acc);
  const float *jin, *vin, *xin;
  int obase;
  size_t am = (size_t)bm * 128;

  if (job == 0) {
    // total1 = -2*x1 + s2@W1^T + x_input@(V0+Eg0)^T + x2@Ed1^T + s1@Bw1n^T
    gemm_term<0>(P.s2      + am * 512,  P.W1  + (size_t)bn * 128 * 512,  nullptr, 512,  As, Bs, acc);
    gemm_term<1>(P.x_input + am * 1024, P.V0  + (size_t)bn * 128 * 1024,
                 P.Eg0 + (size_t)bn * 128 * 1024, 1024, As, Bs, acc);
    gemm_term<0>(P.x2      + am * 512,  P.Ed1 + (size_t)bn * 128 * 512,  nullptr, 512,  As, Bs, acc);
    gemm_term<2>(P.s1      + am * 512,  out + 0 + bn * 128,              nullptr, 512,  As, Bs, acc);
    jin = P.j1; vin = P.v1; xin = P.x1; obase = 0;
  } else {
    // total2 = -2*x2 + y@(W2+Ed2)^T + s1@V1^T + x1@Eg1^T + s2@Bw2n^T
    gemm_term<1>(P.y_target + am * 256, P.W2  + (size_t)bn * 128 * 256,
                 P.Ed2 + (size_t)bn * 128 * 256, 256, As, Bs, acc);
    gemm_term<0>(P.s1      + am * 512,  P.V1  + (size_t)bn * 128 * 512,  nullptr, 512,  As, Bs, acc);
    gemm_term<0>(P.x1      + am * 512,  P.Eg1 + (size_t)bn * 128 * 512,  nullptr, 512,  As, Bs, acc);
    gemm_term<2>(P.s2      + am * 512,  out + 2048 + bn * 128,           nullptr, 512,  As, Bs, acc);
    jin = P.j2; vin = P.v2; xin = P.x2; obase = 2048;
  }

  const int lane = threadIdx.x & 63;
  const int w    = threadIdx.x >> 6;
  const int l16  = lane & 15, lq = lane >> 4;
  const int wm   = (w >> 1) * 64, wn = (w & 1) * 64;

#pragma unroll
  for (int rt = 0; rt < 4; rt++)
#pragma unroll
    for (int ct = 0; ct < 4; ct++)
#pragma unroll
      for (int i = 0; i < 4; i++) {
        int row    = bm * 128 + wm + rt * 16 + lq * 4 + i;
        int col    = bn * 128 + wn + ct * 16 + l16;
        size_t idx = (size_t)row * 512 + col;
        float xf = xin[idx];
        float total = acc[rt][ct][i] - 2.0f * xf;
        float jf = jin[idx];
        float vf = vin[idx];
        jf = jf + 0.1f * (-0.25f * jf + total);
        vf = vf + 0.05f * (-vf + jf);
        float sf = (vf > 0.4f) ? 1.0f : 0.0f;
        vf = vf * (1.0f - sf);
        xf = xf + (-xf / 20.0f + sf);
        size_t ob = (size_t)row * 4096 + obase + col;
        out[ob]        = jf;
        out[ob + 512]  = vf;
        out[ob + 1024] = xf;
        out[ob + 1536] = sf;
      }
}

// ---------------------------------------------------------------------------
extern "C" void kernel_launch(void* const* d_in, const int* in_sizes, int n_in,
                              void* d_out, int out_size, void* d_ws, size_t ws_size,
                              hipStream_t stream)
{
  Params P;
  P.x_input  = (const float*)d_in[0];
  P.y_target = (const float*)d_in[1];
  P.j1 = (const float*)d_in[2];
  P.v1 = (const float*)d_in[3];
  P.s1 = (const float*)d_in[4];
  P.x1 = (const float*)d_in[5];
  P.j2 = (const float*)d_in[6];
  P.v2 = (const float*)d_in[7];
  P.s2 = (const float*)d_in[8];
  P.x2 = (const float*)d_in[9];
  P.W0 = (const float*)d_in[10];
  P.W1 = (const float*)d_in[11];
  P.W2 = (const float*)d_in[12];
  P.V0 = (const float*)d_in[13];
  P.V1 = (const float*)d_in[14];
  P.V2 = (const float*)d_in[15];
  P.Eg0 = (const float*)d_in[16];
  P.Eg1 = (const float*)d_in[17];
  // d_in[18]=Eg2, d_in[19]=Ed0: unused by the reference
  P.Ed1 = (const float*)d_in[20];
  P.Ed2 = (const float*)d_in[21];
  (void)in_sizes; (void)n_in; (void)out_size; (void)d_ws; (void)ws_size;

  float* out = (float*)d_out;
  k_bw<<<dim3(32), dim3(256), 0, stream>>>(P, out);
  k_main<<<dim3(512), dim3(256), 0, stream>>>(P, out, 0);
  k_main<<<dim3(8), dim3(256), 0, stream>>>(P, out, 1);
}

// Round 5
// 476.649 us; speedup vs baseline: 1.3370x; 1.3370x over previous
//
#include <hip/hip_runtime.h>
#include <stdint.h>
#include <stddef.h>

typedef unsigned short u16;
typedef __attribute__((ext_vector_type(8))) short short8;
typedef __attribute__((ext_vector_type(4))) float f32x4;

#define DEVI __device__ __forceinline__

DEVI u16 f2bf(float f) {
  union { float f; unsigned u; } c; c.f = f;
  unsigned r = c.u + 0x7fff + ((c.u >> 16) & 1);
  return (u16)(r >> 16);
}

DEVI short8 pack8(f32x4 a, f32x4 b) {
  short8 v;
#pragma unroll
  for (int i = 0; i < 4; i++) { v[i] = (short)f2bf(a[i]); v[i + 4] = (short)f2bf(b[i]); }
  return v;
}

typedef __attribute__((address_space(1))) const void global_cvoid;
typedef __attribute__((address_space(3))) void lds_void;

// ---------------------------------------------------------------------------
// LDS layout per 128x64 tile: row*64 bf16; 16B granule slot g of row r holds
// global granule g^(r&7)  ->  fragment ds_read_b128 aliases 2-way (free).
// Measured round 4: SQ_LDS_BANK_CONFLICT == 0 with this scheme.
// ---------------------------------------------------------------------------
DEVI void mfma_phase(const u16* As, const u16* Bs, f32x4 acc[4][4])
{
  const int lane = threadIdx.x & 63;
  const int w    = threadIdx.x >> 6;
  const int l16  = lane & 15, lq = lane >> 4;
  const int wm   = (w >> 1) * 64, wn = (w & 1) * 64;
#pragma unroll
  for (int kc = 0; kc < 2; kc++) {
    short8 afr[4], bfr[4];
#pragma unroll
    for (int rt = 0; rt < 4; rt++) {
      int m  = wm + rt * 16 + l16;
      int gr = (kc * 4 + lq) ^ (m & 7);
      afr[rt] = *(const short8*)(As + m * 64 + gr * 8);
    }
#pragma unroll
    for (int ct = 0; ct < 4; ct++) {
      int n  = wn + ct * 16 + l16;
      int gr = (kc * 4 + lq) ^ (n & 7);
      bfr[ct] = *(const short8*)(Bs + n * 64 + gr * 8);
    }
#pragma unroll
    for (int rt = 0; rt < 4; rt++)
#pragma unroll
      for (int ct = 0; ct < 4; ct++)
        acc[rt][ct] = __builtin_amdgcn_mfma_f32_16x16x32_bf16(afr[rt], bfr[ct], acc[rt][ct], 0, 0, 0);
  }
}

DEVI void zero_acc(f32x4 acc[4][4]) {
  f32x4 z = {0.f, 0.f, 0.f, 0.f};
#pragma unroll
  for (int a = 0; a < 4; a++)
#pragma unroll
    for (int b = 0; b < 4; b++) acc[a][b] = z;
}

struct Params {
  const float *x_input, *y_target, *j1, *v1, *s1, *x1, *j2, *v2, *s2, *x2;
  const float *W0, *W1, *W2, *V0, *V1, *V2, *Eg0, *Eg1, *Ed1, *Ed2;
};

// ===========================================================================
// FAST PATH (ws_size >= 59 MB)
// ===========================================================================

// async-DMA stage of one 128x64 bf16 tile; swizzle applied on the GLOBAL
// fetch address (LDS dest of global_load_lds is fixed: base + lane*16B).
DEVI void stage_async(const u16* gbase, int ldr, int k0, u16* lds)
{
  const int t = threadIdx.x;
  const int lane = t & 63, w = t >> 6;
#pragma unroll
  for (int tt = 0; tt < 4; tt++) {
    int rowbase = w * 32 + tt * 8;
    int row = rowbase + (lane >> 3);
    int gsw = (lane & 7) ^ (row & 7);
    __builtin_amdgcn_global_load_lds(
        (global_cvoid*)(gbase + (size_t)row * ldr + k0 + gsw * 8),
        (lds_void*)(lds + rowbase * 64), 16, 0, 0);
  }
}

DEVI void gemm_term_fast(const u16* A, const u16* B, int K,
                         u16* As, u16* Bs, f32x4 acc[4][4])
{
  for (int k0 = 0; k0 < K; k0 += 64) {
    stage_async(A, K, k0, As);
    stage_async(B, K, k0, Bs);
    __syncthreads();   // drains vmcnt(0) -> LDS valid
    mfma_phase(As, Bs, acc);
    __syncthreads();
  }
}

// fp32 NN term for Bw (reads original fp32 weights): acc += A[128,K]*B[K,128col]
DEVI void nn_term(const float* A, const float* B, int K, u16* As, u16* Bs, f32x4 acc[4][4])
{
  const int t  = threadIdx.x;
  const int g  = t & 7, rb = t >> 3;
  const int ks = t >> 4, ng = t & 15;

  for (int k0 = 0; k0 < K; k0 += 64) {
#pragma unroll
    for (int p = 0; p < 4; p++) {          // A: fp32 row-major [*,K] -> bf16 LDS
      int row = p * 32 + rb;
      const float* src = A + (size_t)row * K + k0 + g * 8;
      f32x4 a = *(const f32x4*)src;
      f32x4 b = *(const f32x4*)(src + 4);
      *(short8*)(As + row * 64 + (g ^ (row & 7)) * 8) = pack8(a, b);
    }
#pragma unroll
    for (int i = 0; i < 4; i++) {          // B: fp32 [K,512] col-block, transposed
      int kloc = i * 16 + ks;
      const float* src = B + (size_t)(k0 + kloc) * 512 + ng * 8;
      f32x4 a = *(const f32x4*)src;
      f32x4 b = *(const f32x4*)(src + 4);
#pragma unroll
      for (int e = 0; e < 8; e++) {
        int nloc = ng * 8 + e;
        float val = (e < 4) ? a[e] : b[e - 4];
        Bs[nloc * 64 + ((kloc >> 3) ^ (nloc & 7)) * 8 + (kloc & 7)] = f2bf(val);
      }
    }
    __syncthreads();
    mfma_phase(As, Bs, acc);
    __syncthreads();
  }
}

struct PJob { const float *s0, *s1; u16* dst; int start; };
struct PrepArgs { PJob jb[12]; int prep_blocks; Params P; u16 *Bw1b, *Bw2b; };

// merged: blocks [0,prep_blocks) = fp32->bf16 convert (+optional add);
//         blocks [prep_blocks, +32) = Bw GEMMs -> bf16 ws (co-resident).
__global__ __launch_bounds__(256) void k_prepbw(PrepArgs A)
{
  __shared__ u16 As[128 * 64];
  __shared__ u16 Bs[128 * 64];
  int b = blockIdx.x;
  if (b < A.prep_blocks) {
    int ji = 0;
#pragma unroll
    for (int i = 1; i < 12; i++)
      if (b >= A.jb[i].start) ji = i;
    PJob pj = A.jb[ji];
    size_t e0 = ((size_t)(b - pj.start) * 256 + threadIdx.x) * 8;
    const float* s0 = pj.s0 + e0;
    f32x4 a  = *(const f32x4*)s0;
    f32x4 b4 = *(const f32x4*)(s0 + 4);
    if (pj.s1) {
      const float* s1 = pj.s1 + e0;
      a  = a  + *(const f32x4*)s1;
      b4 = b4 + *(const f32x4*)(s1 + 4);
    }
    *(short8*)(pj.dst + e0) = pack8(a, b4);
    return;
  }
  // Bw part: Bw1 = -(Eg0@W0 + Ed1@V1), Bw2 = -(Eg1@W1 + Ed2@V2), bf16 [512,512]
  int b2  = b - A.prep_blocks;
  int mat = b2 >> 4, loc = b2 & 15;
  int bmw = loc >> 2, bnw = loc & 3;

  f32x4 acc[4][4];
  zero_acc(acc);
  u16* dst;
  if (mat == 0) {
    nn_term(A.P.Eg0 + (size_t)bmw * 128 * 1024, A.P.W0 + bnw * 128, 1024, As, Bs, acc);
    nn_term(A.P.Ed1 + (size_t)bmw * 128 * 512,  A.P.V1 + bnw * 128,  512, As, Bs, acc);
    dst = A.Bw1b;
  } else {
    nn_term(A.P.Eg1 + (size_t)bmw * 128 * 512,  A.P.W1 + bnw * 128,  512, As, Bs, acc);
    nn_term(A.P.Ed2 + (size_t)bmw * 128 * 256,  A.P.V2 + bnw * 128,  256, As, Bs, acc);
    dst = A.Bw2b;
  }
  const int lane = threadIdx.x & 63;
  const int w    = threadIdx.x >> 6;
  const int l16  = lane & 15, lq = lane >> 4;
  const int wm   = (w >> 1) * 64, wn = (w & 1) * 64;
#pragma unroll
  for (int rt = 0; rt < 4; rt++)
#pragma unroll
    for (int ct = 0; ct < 4; ct++)
#pragma unroll
      for (int i = 0; i < 4; i++) {
        int rl = wm + rt * 16 + lq * 4 + i;
        int cl = wn + ct * 16 + l16;
        dst[(size_t)(bmw * 128 + rl) * 512 + bnw * 128 + cl] = f2bf(-acc[rt][ct][i]);
      }
}

struct MJobF {
  const u16* A[4]; const u16* B[4]; int K[4];
  const float *jin, *vin, *xin;
  int obase;
};
struct MArgsF { MJobF j[2]; };

__global__ __launch_bounds__(256) void k_main_fast(MArgsF P, float* __restrict__ out)
{
  __shared__ u16 As[128 * 64];
  __shared__ u16 Bs[128 * 64];
  int job   = blockIdx.x >> 8;
  int local = blockIdx.x & 255;
  int bm = local & 63, bn = local >> 6;
  MJobF jb = P.j[job];

  f32x4 acc[4][4];
  zero_acc(acc);
#pragma unroll
  for (int p = 0; p < 4; p++)
    gemm_term_fast(jb.A[p] + (size_t)bm * 128 * jb.K[p],
                   jb.B[p] + (size_t)bn * 128 * jb.K[p], jb.K[p], As, Bs, acc);

  const int lane = threadIdx.x & 63;
  const int w    = threadIdx.x >> 6;
  const int l16  = lane & 15, lq = lane >> 4;
  const int wm   = (w >> 1) * 64, wn = (w & 1) * 64;

#pragma unroll
  for (int rt = 0; rt < 4; rt++)
#pragma unroll
    for (int ct = 0; ct < 4; ct++)
#pragma unroll
      for (int i = 0; i < 4; i++) {
        int row    = bm * 128 + wm + rt * 16 + lq * 4 + i;
        int col    = bn * 128 + wn + ct * 16 + l16;
        size_t idx = (size_t)row * 512 + col;
        float xf = jb.xin[idx];
        float total = acc[rt][ct][i] - 2.0f * xf;
        float jf = jb.jin[idx];
        float vf = jb.vin[idx];
        jf = jf + 0.1f * (-0.25f * jf + total);
        vf = vf + 0.05f * (-vf + jf);
        float sf = (vf > 0.4f) ? 1.0f : 0.0f;
        vf = vf * (1.0f - sf);
        xf = xf + (-xf / 20.0f + sf);
        size_t ob = (size_t)row * 4096 + jb.obase + col;
        out[ob]        = jf;
        out[ob + 512]  = vf;
        out[ob + 1024] = xf;
        out[ob + 1536] = sf;
      }
}

// ===========================================================================
// FALLBACK PATH (round-4 verbatim; used only if ws_size < 59 MB)
// ===========================================================================

DEVI void stage_A_fb(const float* A, int ldr, int k0, u16* dst)
{
  const int t = threadIdx.x;
  const int g = t & 7, rb = t >> 3;
#pragma unroll
  for (int p = 0; p < 4; p++) {
    int row = p * 32 + rb;
    const float* src = A + (size_t)row * ldr + k0 + g * 8;
    f32x4 a = *(const f32x4*)src;
    f32x4 b = *(const f32x4*)(src + 4);
    *(short8*)(dst + row * 64 + (g ^ (row & 7)) * 8) = pack8(a, b);
  }
}

template <int MODE>
DEVI void gemm_term_fb(const float* A, const float* B0, const float* B1, int K,
                       u16* As, u16* Bs, f32x4 acc[4][4])
{
  const int t = threadIdx.x;
  const int g = t & 7, rb = t >> 3;
  for (int k0 = 0; k0 < K; k0 += 64) {
    stage_A_fb(A, K, k0, As);
#pragma unroll
    for (int p = 0; p < 4; p++) {
      int row = p * 32 + rb;
      const float* src;
      if (MODE == 2) src = B0 + (size_t)row * 4096 + (k0 >> 7) * 512 + (k0 & 127) + g * 8;
      else           src = B0 + (size_t)row * K + k0 + g * 8;
      f32x4 a = *(const f32x4*)src;
      f32x4 b = *(const f32x4*)(src + 4);
      if (MODE == 1) {
        const float* s2 = B1 + (size_t)row * K + k0 + g * 8;
        a = a + *(const f32x4*)s2;
        b = b + *(const f32x4*)(s2 + 4);
      }
      *(short8*)(Bs + row * 64 + (g ^ (row & 7)) * 8) = pack8(a, b);
    }
    __syncthreads();
    mfma_phase(As, Bs, acc);
    __syncthreads();
  }
}

__global__ __launch_bounds__(256) void k_bw_fb(Params P, float* __restrict__ out)
{
  __shared__ u16 As[128 * 64];
  __shared__ u16 Bs[128 * 64];
  int b   = blockIdx.x;
  int mat = b >> 4, loc = b & 15;
  int bmw = loc >> 2, bnw = loc & 3;

  f32x4 acc[4][4];
  zero_acc(acc);
  int obase;
  if (mat == 0) {
    nn_term(P.Eg0 + (size_t)bmw * 128 * 1024, P.W0 + bnw * 128, 1024, As, Bs, acc);
    nn_term(P.Ed1 + (size_t)bmw * 128 * 512,  P.V1 + bnw * 128,  512, As, Bs, acc);
    obase = 0;
  } else {
    nn_term(P.Eg1 + (size_t)bmw * 128 * 512,  P.W1 + bnw * 128,  512, As, Bs, acc);
    nn_term(P.Ed2 + (size_t)bmw * 128 * 256,  P.V2 + bnw * 128,  256, As, Bs, acc);
    obase = 2048;
  }
  const int lane = threadIdx.x & 63;
  const int w    = threadIdx.x >> 6;
  const int l16  = lane & 15, lq = lane >> 4;
  const int wm   = (w >> 1) * 64, wn = (w & 1) * 64;
#pragma unroll
  for (int rt = 0; rt < 4; rt++)
#pragma unroll
    for (int ct = 0; ct < 4; ct++)
#pragma unroll
      for (int i = 0; i < 4; i++) {
        int rl = wm + rt * 16 + lq * 4 + i;
        int cl = wn + ct * 16 + l16;
        out[(size_t)rl * 4096 + obase + bmw * 128 + bnw * 512 + cl] = -acc[rt][ct][i];
      }
}

__global__ __launch_bounds__(256) void k_main_fb(Params P, float* __restrict__ out, int fix)
{
  __shared__ u16 As[128 * 64];
  __shared__ u16 Bs[128 * 64];
  int job, bm, bn;
  if (fix) {
    job = blockIdx.x >> 2; bn = blockIdx.x & 3; bm = 0;
  } else {
    job = blockIdx.x >> 8;
    int local = blockIdx.x & 255;
    bm = local & 63; bn = local >> 6;
    if (bm == 0) return;
  }

  f32x4 acc[4][4];
  zero_acc(acc);
  const float *jin, *vin, *xin;
  int obase;
  size_t am = (size_t)bm * 128;

  if (job == 0) {
    gemm_term_fb<0>(P.s2      + am * 512,  P.W1  + (size_t)bn * 128 * 512,  nullptr, 512,  As, Bs, acc);
    gemm_term_fb<1>(P.x_input + am * 1024, P.V0  + (size_t)bn * 128 * 1024,
                    P.Eg0 + (size_t)bn * 128 * 1024, 1024, As, Bs, acc);
    gemm_term_fb<0>(P.x2      + am * 512,  P.Ed1 + (size_t)bn * 128 * 512,  nullptr, 512,  As, Bs, acc);
    gemm_term_fb<2>(P.s1      + am * 512,  out + 0 + bn * 128,              nullptr, 512,  As, Bs, acc);
    jin = P.j1; vin = P.v1; xin = P.x1; obase = 0;
  } else {
    gemm_term_fb<1>(P.y_target + am * 256, P.W2  + (size_t)bn * 128 * 256,
                    P.Ed2 + (size_t)bn * 128 * 256, 256, As, Bs, acc);
    gemm_term_fb<0>(P.s1      + am * 512,  P.V1  + (size_t)bn * 128 * 512,  nullptr, 512,  As, Bs, acc);
    gemm_term_fb<0>(P.x1      + am * 512,  P.Eg1 + (size_t)bn * 128 * 512,  nullptr, 512,  As, Bs, acc);
    gemm_term_fb<2>(P.s2      + am * 512,  out + 2048 + bn * 128,           nullptr, 512,  As, Bs, acc);
    jin = P.j2; vin = P.v2; xin = P.x2; obase = 2048;
  }

  const int lane = threadIdx.x & 63;
  const int w    = threadIdx.x >> 6;
  const int l16  = lane & 15, lq = lane >> 4;
  const int wm   = (w >> 1) * 64, wn = (w & 1) * 64;

#pragma unroll
  for (int rt = 0; rt < 4; rt++)
#pragma unroll
    for (int ct = 0; ct < 4; ct++)
#pragma unroll
      for (int i = 0; i < 4; i++) {
        int row    = bm * 128 + wm + rt * 16 + lq * 4 + i;
        int col    = bn * 128 + wn + ct * 16 + l16;
        size_t idx = (size_t)row * 512 + col;
        float xf = xin[idx];
        float total = acc[rt][ct][i] - 2.0f * xf;
        float jf = jin[idx];
        float vf = vin[idx];
        jf = jf + 0.1f * (-0.25f * jf + total);
        vf = vf + 0.05f * (-vf + jf);
        float sf = (vf > 0.4f) ? 1.0f : 0.0f;
        vf = vf * (1.0f - sf);
        xf = xf + (-xf / 20.0f + sf);
        size_t ob = (size_t)row * 4096 + obase + col;
        out[ob]        = jf;
        out[ob + 512]  = vf;
        out[ob + 1024] = xf;
        out[ob + 1536] = sf;
      }
}

// ---------------------------------------------------------------------------
extern "C" void kernel_launch(void* const* d_in, const int* in_sizes, int n_in,
                              void* d_out, int out_size, void* d_ws, size_t ws_size,
                              hipStream_t stream)
{
  Params P;
  P.x_input  = (const float*)d_in[0];
  P.y_target = (const float*)d_in[1];
  P.j1 = (const float*)d_in[2];
  P.v1 = (const float*)d_in[3];
  P.s1 = (const float*)d_in[4];
  P.x1 = (const float*)d_in[5];
  P.j2 = (const float*)d_in[6];
  P.v2 = (const float*)d_in[7];
  P.s2 = (const float*)d_in[8];
  P.x2 = (const float*)d_in[9];
  P.W0 = (const float*)d_in[10];
  P.W1 = (const float*)d_in[11];
  P.W2 = (const float*)d_in[12];
  P.V0 = (const float*)d_in[13];
  P.V1 = (const float*)d_in[14];
  P.V2 = (const float*)d_in[15];
  P.Eg0 = (const float*)d_in[16];
  P.Eg1 = (const float*)d_in[17];
  P.Ed1 = (const float*)d_in[20];
  P.Ed2 = (const float*)d_in[21];
  (void)in_sizes; (void)n_in; (void)out_size;

  float* out = (float*)d_out;

  if (ws_size >= 58982400) {
    // ---- fast path: bf16 operand cache in ws ----
    char* ws = (char*)d_ws;
    u16* xin_b = (u16*)(ws + 0);         // [8192,1024]
    u16* y_b   = (u16*)(ws + 16777216);  // [8192,256]
    u16* s1_b  = (u16*)(ws + 20971520);  // [8192,512]
    u16* x1_b  = (u16*)(ws + 29360128);
    u16* s2_b  = (u16*)(ws + 37748736);
    u16* x2_b  = (u16*)(ws + 46137344);
    u16* W1_b  = (u16*)(ws + 54525952);  // [512,512]
    u16* P1_b  = (u16*)(ws + 55050240);  // [512,1024] = V0+Eg0
    u16* Ed1_b = (u16*)(ws + 56098816);  // [512,512]
    u16* V1_b  = (u16*)(ws + 56623104);
    u16* Eg1_b = (u16*)(ws + 57147392);
    u16* P2_b  = (u16*)(ws + 57671680);  // [512,256] = W2+Ed2
    u16* Bw1_b = (u16*)(ws + 57933824);  // [512,512]
    u16* Bw2_b = (u16*)(ws + 58458112);  // [512,512]

    PrepArgs pa;
    pa.jb[0]  = { P.x_input,  nullptr, xin_b,     0 };
    pa.jb[1]  = { P.y_target, nullptr, y_b,    4096 };
    pa.jb[2]  = { P.s1,       nullptr, s1_b,   5120 };
    pa.jb[3]  = { P.x1,       nullptr, x1_b,   7168 };
    pa.jb[4]  = { P.s2,       nullptr, s2_b,   9216 };
    pa.jb[5]  = { P.x2,       nullptr, x2_b,  11264 };
    pa.jb[6]  = { P.W1,       nullptr, W1_b,  13312 };
    pa.jb[7]  = { P.V0,       P.Eg0,   P1_b,  13440 };
    pa.jb[8]  = { P.Ed1,      nullptr, Ed1_b, 13696 };
    pa.jb[9]  = { P.V1,       nullptr, V1_b,  13824 };
    pa.jb[10] = { P.Eg1,      nullptr, Eg1_b, 13952 };
    pa.jb[11] = { P.W2,       P.Ed2,   P2_b,  14080 };
    pa.prep_blocks = 14144;
    pa.P = P; pa.Bw1b = Bw1_b; pa.Bw2b = Bw2_b;
    k_prepbw<<<dim3(14176), dim3(256), 0, stream>>>(pa);

    MArgsF ma;
    ma.j[0].A[0] = s2_b;  ma.j[0].B[0] = W1_b;  ma.j[0].K[0] = 512;
    ma.j[0].A[1] = xin_b; ma.j[0].B[1] = P1_b;  ma.j[0].K[1] = 1024;
    ma.j[0].A[2] = x2_b;  ma.j[0].B[2] = Ed1_b; ma.j[0].K[2] = 512;
    ma.j[0].A[3] = s1_b;  ma.j[0].B[3] = Bw1_b; ma.j[0].K[3] = 512;
    ma.j[0].jin = P.j1; ma.j[0].vin = P.v1; ma.j[0].xin = P.x1; ma.j[0].obase = 0;
    ma.j[1].A[0] = y_b;   ma.j[1].B[0] = P2_b;  ma.j[1].K[0] = 256;
    ma.j[1].A[1] = s1_b;  ma.j[1].B[1] = V1_b;  ma.j[1].K[1] = 512;
    ma.j[1].A[2] = x1_b;  ma.j[1].B[2] = Eg1_b; ma.j[1].K[2] = 512;
    ma.j[1].A[3] = s2_b;  ma.j[1].B[3] = Bw2_b; ma.j[1].K[3] = 512;
    ma.j[1].jin = P.j2; ma.j[1].vin = P.v2; ma.j[1].xin = P.x2; ma.j[1].obase = 2048;
    k_main_fast<<<dim3(512), dim3(256), 0, stream>>>(ma, out);
  } else {
    // ---- fallback: proven round-4 path ----
    k_bw_fb<<<dim3(32), dim3(256), 0, stream>>>(P, out);
    k_main_fb<<<dim3(512), dim3(256), 0, stream>>>(P, out, 0);
    k_main_fb<<<dim3(8), dim3(256), 0, stream>>>(P, out, 1);
  }
}

// Round 6
// 413.758 us; speedup vs baseline: 1.5402x; 1.1520x over previous
//
#include <hip/hip_runtime.h>
#include <stdint.h>
#include <stddef.h>

typedef unsigned short u16;
typedef __attribute__((ext_vector_type(8))) short short8;
typedef __attribute__((ext_vector_type(4))) float f32x4;

#define DEVI __device__ __forceinline__

DEVI u16 f2bf(float f) {
  union { float f; unsigned u; } c; c.f = f;
  unsigned r = c.u + 0x7fff + ((c.u >> 16) & 1);
  return (u16)(r >> 16);
}

DEVI short8 pack8(f32x4 a, f32x4 b) {
  short8 v;
#pragma unroll
  for (int i = 0; i < 4; i++) { v[i] = (short)f2bf(a[i]); v[i + 4] = (short)f2bf(b[i]); }
  return v;
}

typedef __attribute__((address_space(1))) const void global_cvoid;
typedef __attribute__((address_space(3))) void lds_void;

// ---------------------------------------------------------------------------
// LDS layout per 128x64 tile: row*64 bf16; 16B granule slot g of row r holds
// global granule g^(r&7) -> fragment ds_read_b128 aliases 2-way (free).
// Measured: SQ_LDS_BANK_CONFLICT == 0 with this scheme (round 4).
// ---------------------------------------------------------------------------
DEVI void mfma_phase(const u16* As, const u16* Bs, f32x4 acc[4][4])
{
  const int lane = threadIdx.x & 63;
  const int w    = threadIdx.x >> 6;
  const int l16  = lane & 15, lq = lane >> 4;
  const int wm   = (w >> 1) * 64, wn = (w & 1) * 64;
#pragma unroll
  for (int kc = 0; kc < 2; kc++) {
    short8 afr[4], bfr[4];
#pragma unroll
    for (int rt = 0; rt < 4; rt++) {
      int m  = wm + rt * 16 + l16;
      int gr = (kc * 4 + lq) ^ (m & 7);
      afr[rt] = *(const short8*)(As + m * 64 + gr * 8);
    }
#pragma unroll
    for (int ct = 0; ct < 4; ct++) {
      int n  = wn + ct * 16 + l16;
      int gr = (kc * 4 + lq) ^ (n & 7);
      bfr[ct] = *(const short8*)(Bs + n * 64 + gr * 8);
    }
#pragma unroll
    for (int rt = 0; rt < 4; rt++)
#pragma unroll
      for (int ct = 0; ct < 4; ct++)
        acc[rt][ct] = __builtin_amdgcn_mfma_f32_16x16x32_bf16(afr[rt], bfr[ct], acc[rt][ct], 0, 0, 0);
  }
}

DEVI void zero_acc(f32x4 acc[4][4]) {
  f32x4 z = {0.f, 0.f, 0.f, 0.f};
#pragma unroll
  for (int a = 0; a < 4; a++)
#pragma unroll
    for (int b = 0; b < 4; b++) acc[a][b] = z;
}

struct Params {
  const float *x_input, *y_target, *j1, *v1, *s1, *x1, *j2, *v2, *s2, *x2;
  const float *W0, *W1, *W2, *V0, *V1, *V2, *Eg0, *Eg1, *Ed1, *Ed2;
};

// ===========================================================================
// FAST PATH (ws_size >= 62652416)
// ===========================================================================

// async-DMA stage of one 128x64 bf16 tile; swizzle applied on the GLOBAL
// fetch address (LDS dest of global_load_lds is fixed: base + lane*16B).
DEVI void stage_async(const u16* gbase, int ldr, int k0, u16* lds)
{
  const int t = threadIdx.x;
  const int lane = t & 63, w = t >> 6;
#pragma unroll
  for (int tt = 0; tt < 4; tt++) {
    int rowbase = w * 32 + tt * 8;
    int row = rowbase + (lane >> 3);
    int gsw = (lane & 7) ^ (row & 7);
    __builtin_amdgcn_global_load_lds(
        (global_cvoid*)(gbase + (size_t)row * ldr + k0 + gsw * 8),
        (lds_void*)(lds + rowbase * 64), 16, 0, 0);
  }
}

DEVI void gemm_term_fast(const u16* A, const u16* B, int K,
                         u16* As, u16* Bs, f32x4 acc[4][4])
{
  for (int k0 = 0; k0 < K; k0 += 64) {
    stage_async(A, K, k0, As);
    stage_async(B, K, k0, Bs);
    __syncthreads();
    mfma_phase(As, Bs, acc);
    __syncthreads();
  }
}

// ---------------------------------------------------------------------------
// k_prep: blocks [0,14464): fp32->bf16 convert (+optional add), 2048 elem/blk
//         blocks [14464,15616): 32x32 transpose tiles W0/V1/W1/V2 -> bf16
// ---------------------------------------------------------------------------
struct PJob { const float *s0, *s1; u16* dst; int start; };
struct TJob { const float* in; u16* out; int J, tbase; };
struct PrepArgs { PJob jb[14]; TJob tj[4]; };

__global__ __launch_bounds__(256) void k_prep(PrepArgs A)
{
  __shared__ u16 T[32][33];
  int b = blockIdx.x;
  int t = threadIdx.x;
  if (b < 14464) {
    int ji = 0;
#pragma unroll
    for (int i = 1; i < 14; i++)
      if (b >= A.jb[i].start) ji = i;
    PJob pj = A.jb[ji];
    size_t e0 = ((size_t)(b - pj.start) * 256 + t) * 8;
    const float* s0 = pj.s0 + e0;
    f32x4 a  = *(const f32x4*)s0;
    f32x4 b4 = *(const f32x4*)(s0 + 4);
    if (pj.s1) {
      const float* s1 = pj.s1 + e0;
      a  = a  + *(const f32x4*)s1;
      b4 = b4 + *(const f32x4*)(s1 + 4);
    }
    *(short8*)(pj.dst + e0) = pack8(a, b4);
    return;
  }
  // transpose tiles: in fp32 [J,512] -> out bf16 [512,J]
  int b2 = b - 14464;
  int ji = 0;
#pragma unroll
  for (int i = 1; i < 4; i++)
    if (b2 >= A.tj[i].tbase) ji = i;
  TJob jb = A.tj[ji];
  int local = b2 - jb.tbase;
  int tm = local >> 4;          // J/32 tile rows
  int tk = local & 15;          // 512/32 tile cols
  int tx = t & 31, ty = t >> 5; // ty 0..7
#pragma unroll
  for (int i = 0; i < 4; i++) {
    int r = ty + i * 8;
    T[r][tx] = f2bf(jb.in[(size_t)(tm * 32 + r) * 512 + tk * 32 + tx]);
  }
  __syncthreads();
#pragma unroll
  for (int i = 0; i < 4; i++) {
    int r = ty + i * 8;
    jb.out[(size_t)(tk * 32 + r) * jb.J + tm * 32 + tx] = T[tx][r];
  }
}

// ---------------------------------------------------------------------------
// k_bw2: Bw1 = -(Eg0@W0 + Ed1@V1), Bw2 = -(Eg1@W1 + Ed2@V2)  [512,512] bf16,
// TN form from pre-converted/transposed bf16 operands. 32 blocks.
// ---------------------------------------------------------------------------
struct BW2Args {
  const u16 *Eg0b, *W0tb, *Ed1b, *V1tb, *Eg1b, *W1tb, *Ed2b, *V2tb;
  u16 *Bw1b, *Bw2b;
};

__global__ __launch_bounds__(256) void k_bw2(BW2Args A)
{
  __shared__ u16 As[128 * 64];
  __shared__ u16 Bs[128 * 64];
  int b   = blockIdx.x;
  int mat = b >> 4, loc = b & 15;
  int bmw = loc >> 2, bnw = loc & 3;

  f32x4 acc[4][4];
  zero_acc(acc);
  u16* dst;
  if (mat == 0) {
    gemm_term_fast(A.Eg0b + (size_t)bmw * 128 * 1024, A.W0tb + (size_t)bnw * 128 * 1024, 1024, As, Bs, acc);
    gemm_term_fast(A.Ed1b + (size_t)bmw * 128 * 512,  A.V1tb + (size_t)bnw * 128 * 512,   512, As, Bs, acc);
    dst = A.Bw1b;
  } else {
    gemm_term_fast(A.Eg1b + (size_t)bmw * 128 * 512,  A.W1tb + (size_t)bnw * 128 * 512,   512, As, Bs, acc);
    gemm_term_fast(A.Ed2b + (size_t)bmw * 128 * 256,  A.V2tb + (size_t)bnw * 128 * 256,   256, As, Bs, acc);
    dst = A.Bw2b;
  }
  const int lane = threadIdx.x & 63;
  const int w    = threadIdx.x >> 6;
  const int l16  = lane & 15, lq = lane >> 4;
  const int wm   = (w >> 1) * 64, wn = (w & 1) * 64;
#pragma unroll
  for (int rt = 0; rt < 4; rt++)
#pragma unroll
    for (int ct = 0; ct < 4; ct++)
#pragma unroll
      for (int i = 0; i < 4; i++) {
        int rl = wm + rt * 16 + lq * 4 + i;
        int cl = wn + ct * 16 + l16;
        dst[(size_t)(bmw * 128 + rl) * 512 + bnw * 128 + cl] = f2bf(-acc[rt][ct][i]);
      }
}

// ---------------------------------------------------------------------------
// k_main_fast: per layer total = 4 TN GEMM terms (bf16 ws operands), fused LIF
// ---------------------------------------------------------------------------
struct MJobF {
  const u16* A[4]; const u16* B[4]; int K[4];
  const float *jin, *vin, *xin;
  int obase;
};
struct MArgsF { MJobF j[2]; };

__global__ __launch_bounds__(256) void k_main_fast(MArgsF P, float* __restrict__ out)
{
  __shared__ u16 As[128 * 64];
  __shared__ u16 Bs[128 * 64];
  int job   = blockIdx.x >> 8;
  int local = blockIdx.x & 255;
  int bm = local & 63, bn = local >> 6;
  MJobF jb = P.j[job];

  f32x4 acc[4][4];
  zero_acc(acc);
#pragma unroll
  for (int p = 0; p < 4; p++)
    gemm_term_fast(jb.A[p] + (size_t)bm * 128 * jb.K[p],
                   jb.B[p] + (size_t)bn * 128 * jb.K[p], jb.K[p], As, Bs, acc);

  const int lane = threadIdx.x & 63;
  const int w    = threadIdx.x >> 6;
  const int l16  = lane & 15, lq = lane >> 4;
  const int wm   = (w >> 1) * 64, wn = (w & 1) * 64;

#pragma unroll
  for (int rt = 0; rt < 4; rt++)
#pragma unroll
    for (int ct = 0; ct < 4; ct++)
#pragma unroll
      for (int i = 0; i < 4; i++) {
        int row    = bm * 128 + wm + rt * 16 + lq * 4 + i;
        int col    = bn * 128 + wn + ct * 16 + l16;
        size_t idx = (size_t)row * 512 + col;
        float xf = jb.xin[idx];
        float total = acc[rt][ct][i] - 2.0f * xf;
        float jf = jb.jin[idx];
        float vf = jb.vin[idx];
        jf = jf + 0.1f * (-0.25f * jf + total);
        vf = vf + 0.05f * (-vf + jf);
        float sf = (vf > 0.4f) ? 1.0f : 0.0f;
        vf = vf * (1.0f - sf);
        xf = xf + (-xf / 20.0f + sf);
        size_t ob = (size_t)row * 4096 + jb.obase + col;
        out[ob]        = jf;
        out[ob + 512]  = vf;
        out[ob + 1024] = xf;
        out[ob + 1536] = sf;
      }
}

// ===========================================================================
// FALLBACK PATH (round-4 verbatim; used only if ws_size < 62652416)
// ===========================================================================

DEVI void stage_A_fb(const float* A, int ldr, int k0, u16* dst)
{
  const int t = threadIdx.x;
  const int g = t & 7, rb = t >> 3;
#pragma unroll
  for (int p = 0; p < 4; p++) {
    int row = p * 32 + rb;
    const float* src = A + (size_t)row * ldr + k0 + g * 8;
    f32x4 a = *(const f32x4*)src;
    f32x4 b = *(const f32x4*)(src + 4);
    *(short8*)(dst + row * 64 + (g ^ (row & 7)) * 8) = pack8(a, b);
  }
}

DEVI void nn_term_fb(const float* A, const float* B, int K, u16* As, u16* Bs, f32x4 acc[4][4])
{
  const int t  = threadIdx.x;
  const int ks = t >> 4, ng = t & 15;
  for (int k0 = 0; k0 < K; k0 += 64) {
    stage_A_fb(A, K, k0, As);
#pragma unroll
    for (int i = 0; i < 4; i++) {
      int kloc = i * 16 + ks;
      const float* src = B + (size_t)(k0 + kloc) * 512 + ng * 8;
      f32x4 a = *(const f32x4*)src;
      f32x4 b = *(const f32x4*)(src + 4);
#pragma unroll
      for (int e = 0; e < 8; e++) {
        int nloc = ng * 8 + e;
        float val = (e < 4) ? a[e] : b[e - 4];
        Bs[nloc * 64 + ((kloc >> 3) ^ (nloc & 7)) * 8 + (kloc & 7)] = f2bf(val);
      }
    }
    __syncthreads();
    mfma_phase(As, Bs, acc);
    __syncthreads();
  }
}

template <int MODE>
DEVI void gemm_term_fb(const float* A, const float* B0, const float* B1, int K,
                       u16* As, u16* Bs, f32x4 acc[4][4])
{
  const int t = threadIdx.x;
  const int g = t & 7, rb = t >> 3;
  for (int k0 = 0; k0 < K; k0 += 64) {
    stage_A_fb(A, K, k0, As);
#pragma unroll
    for (int p = 0; p < 4; p++) {
      int row = p * 32 + rb;
      const float* src;
      if (MODE == 2) src = B0 + (size_t)row * 4096 + (k0 >> 7) * 512 + (k0 & 127) + g * 8;
      else           src = B0 + (size_t)row * K + k0 + g * 8;
      f32x4 a = *(const f32x4*)src;
      f32x4 b = *(const f32x4*)(src + 4);
      if (MODE == 1) {
        const float* s2 = B1 + (size_t)row * K + k0 + g * 8;
        a = a + *(const f32x4*)s2;
        b = b + *(const f32x4*)(s2 + 4);
      }
      *(short8*)(Bs + row * 64 + (g ^ (row & 7)) * 8) = pack8(a, b);
    }
    __syncthreads();
    mfma_phase(As, Bs, acc);
    __syncthreads();
  }
}

__global__ __launch_bounds__(256) void k_bw_fb(Params P, float* __restrict__ out)
{
  __shared__ u16 As[128 * 64];
  __shared__ u16 Bs[128 * 64];
  int b   = blockIdx.x;
  int mat = b >> 4, loc = b & 15;
  int bmw = loc >> 2, bnw = loc & 3;

  f32x4 acc[4][4];
  zero_acc(acc);
  int obase;
  if (mat == 0) {
    nn_term_fb(P.Eg0 + (size_t)bmw * 128 * 1024, P.W0 + bnw * 128, 1024, As, Bs, acc);
    nn_term_fb(P.Ed1 + (size_t)bmw * 128 * 512,  P.V1 + bnw * 128,  512, As, Bs, acc);
    obase = 0;
  } else {
    nn_term_fb(P.Eg1 + (size_t)bmw * 128 * 512,  P.W1 + bnw * 128,  512, As, Bs, acc);
    nn_term_fb(P.Ed2 + (size_t)bmw * 128 * 256,  P.V2 + bnw * 128,  256, As, Bs, acc);
    obase = 2048;
  }
  const int lane = threadIdx.x & 63;
  const int w    = threadIdx.x >> 6;
  const int l16  = lane & 15, lq = lane >> 4;
  const int wm   = (w >> 1) * 64, wn = (w & 1) * 64;
#pragma unroll
  for (int rt = 0; rt < 4; rt++)
#pragma unroll
    for (int ct = 0; ct < 4; ct++)
#pragma unroll
      for (int i = 0; i < 4; i++) {
        int rl = wm + rt * 16 + lq * 4 + i;
        int cl = wn + ct * 16 + l16;
        out[(size_t)rl * 4096 + obase + bmw * 128 + bnw * 512 + cl] = -acc[rt][ct][i];
      }
}

__global__ __launch_bounds__(256) void k_main_fb(Params P, float* __restrict__ out, int fix)
{
  __shared__ u16 As[128 * 64];
  __shared__ u16 Bs[128 * 64];
  int job, bm, bn;
  if (fix) {
    job = blockIdx.x >> 2; bn = blockIdx.x & 3; bm = 0;
  } else {
    job = blockIdx.x >> 8;
    int local = blockIdx.x & 255;
    bm = local & 63; bn = local >> 6;
    if (bm == 0) return;
  }

  f32x4 acc[4][4];
  zero_acc(acc);
  const float *jin, *vin, *xin;
  int obase;
  size_t am = (size_t)bm * 128;

  if (job == 0) {
    gemm_term_fb<0>(P.s2      + am * 512,  P.W1  + (size_t)bn * 128 * 512,  nullptr, 512,  As, Bs, acc);
    gemm_term_fb<1>(P.x_input + am * 1024, P.V0  + (size_t)bn * 128 * 1024,
                    P.Eg0 + (size_t)bn * 128 * 1024, 1024, As, Bs, acc);
    gemm_term_fb<0>(P.x2      + am * 512,  P.Ed1 + (size_t)bn * 128 * 512,  nullptr, 512,  As, Bs, acc);
    gemm_term_fb<2>(P.s1      + am * 512,  out + 0 + bn * 128,              nullptr, 512,  As, Bs, acc);
    jin = P.j1; vin = P.v1; xin = P.x1; obase = 0;
  } else {
    gemm_term_fb<1>(P.y_target + am * 256, P.W2  + (size_t)bn * 128 * 256,
                    P.Ed2 + (size_t)bn * 128 * 256, 256, As, Bs, acc);
    gemm_term_fb<0>(P.s1      + am * 512,  P.V1  + (size_t)bn * 128 * 512,  nullptr, 512,  As, Bs, acc);
    gemm_term_fb<0>(P.x1      + am * 512,  P.Eg1 + (size_t)bn * 128 * 512,  nullptr, 512,  As, Bs, acc);
    gemm_term_fb<2>(P.s2      + am * 512,  out + 2048 + bn * 128,           nullptr, 512,  As, Bs, acc);
    jin = P.j2; vin = P.v2; xin = P.x2; obase = 2048;
  }

  const int lane = threadIdx.x & 63;
  const int w    = threadIdx.x >> 6;
  const int l16  = lane & 15, lq = lane >> 4;
  const int wm   = (w >> 1) * 64, wn = (w & 1) * 64;

#pragma unroll
  for (int rt = 0; rt < 4; rt++)
#pragma unroll
    for (int ct = 0; ct < 4; ct++)
#pragma unroll
      for (int i = 0; i < 4; i++) {
        int row    = bm * 128 + wm + rt * 16 + lq * 4 + i;
        int col    = bn * 128 + wn + ct * 16 + l16;
        size_t idx = (size_t)row * 512 + col;
        float xf = xin[idx];
        float total = acc[rt][ct][i] - 2.0f * xf;
        float jf = jin[idx];
        float vf = vin[idx];
        jf = jf + 0.1f * (-0.25f * jf + total);
        vf = vf + 0.05f * (-vf + jf);
        float sf = (vf > 0.4f) ? 1.0f : 0.0f;
        vf = vf * (1.0f - sf);
        xf = xf + (-xf / 20.0f + sf);
        size_t ob = (size_t)row * 4096 + obase + col;
        out[ob]        = jf;
        out[ob + 512]  = vf;
        out[ob + 1024] = xf;
        out[ob + 1536] = sf;
      }
}

// ---------------------------------------------------------------------------
extern "C" void kernel_launch(void* const* d_in, const int* in_sizes, int n_in,
                              void* d_out, int out_size, void* d_ws, size_t ws_size,
                              hipStream_t stream)
{
  Params P;
  P.x_input  = (const float*)d_in[0];
  P.y_target = (const float*)d_in[1];
  P.j1 = (const float*)d_in[2];
  P.v1 = (const float*)d_in[3];
  P.s1 = (const float*)d_in[4];
  P.x1 = (const float*)d_in[5];
  P.j2 = (const float*)d_in[6];
  P.v2 = (const float*)d_in[7];
  P.s2 = (const float*)d_in[8];
  P.x2 = (const float*)d_in[9];
  P.W0 = (const float*)d_in[10];
  P.W1 = (const float*)d_in[11];
  P.W2 = (const float*)d_in[12];
  P.V0 = (const float*)d_in[13];
  P.V1 = (const float*)d_in[14];
  P.V2 = (const float*)d_in[15];
  P.Eg0 = (const float*)d_in[16];
  P.Eg1 = (const float*)d_in[17];
  P.Ed1 = (const float*)d_in[20];
  P.Ed2 = (const float*)d_in[21];
  (void)in_sizes; (void)n_in; (void)out_size;

  float* out = (float*)d_out;

  if (ws_size >= 62652416) {
    char* ws = (char*)d_ws;
    u16* xin_b = (u16*)(ws + 0);         // [8192,1024]
    u16* y_b   = (u16*)(ws + 16777216);  // [8192,256]
    u16* s1_b  = (u16*)(ws + 20971520);  // [8192,512]
    u16* x1_b  = (u16*)(ws + 29360128);
    u16* s2_b  = (u16*)(ws + 37748736);
    u16* x2_b  = (u16*)(ws + 46137344);
    u16* W1_b  = (u16*)(ws + 54525952);  // [512,512]
    u16* P1_b  = (u16*)(ws + 55050240);  // [512,1024] = V0+Eg0
    u16* Ed1_b = (u16*)(ws + 56098816);  // [512,512]
    u16* V1_b  = (u16*)(ws + 56623104);
    u16* Eg1_b = (u16*)(ws + 57147392);
    u16* P2_b  = (u16*)(ws + 57671680);  // [512,256] = W2+Ed2
    u16* Bw1_b = (u16*)(ws + 57933824);  // [512,512]
    u16* Bw2_b = (u16*)(ws + 58458112);  // [512,512]
    u16* W0t_b = (u16*)(ws + 58982400);  // [512,1024]
    u16* V1t_b = (u16*)(ws + 60030976);  // [512,512]
    u16* W1t_b = (u16*)(ws + 60555264);  // [512,512]
    u16* V2t_b = (u16*)(ws + 61079552);  // [512,256]
    u16* Eg0_b = (u16*)(ws + 61341696);  // [512,1024]
    u16* Ed2_b = (u16*)(ws + 62390272);  // [512,256]  (end 62652416)

    PrepArgs pa;
    pa.jb[0]  = { P.x_input,  nullptr, xin_b,     0 };
    pa.jb[1]  = { P.y_target, nullptr, y_b,    4096 };
    pa.jb[2]  = { P.s1,       nullptr, s1_b,   5120 };
    pa.jb[3]  = { P.x1,       nullptr, x1_b,   7168 };
    pa.jb[4]  = { P.s2,       nullptr, s2_b,   9216 };
    pa.jb[5]  = { P.x2,       nullptr, x2_b,  11264 };
    pa.jb[6]  = { P.W1,       nullptr, W1_b,  13312 };
    pa.jb[7]  = { P.V0,       P.Eg0,   P1_b,  13440 };
    pa.jb[8]  = { P.Ed1,      nullptr, Ed1_b, 13696 };
    pa.jb[9]  = { P.V1,       nullptr, V1_b,  13824 };
    pa.jb[10] = { P.Eg1,      nullptr, Eg1_b, 13952 };
    pa.jb[11] = { P.W2,       P.Ed2,   P2_b,  14080 };
    pa.jb[12] = { P.Eg0,      nullptr, Eg0_b, 14144 };
    pa.jb[13] = { P.Ed2,      nullptr, Ed2_b, 14400 };   // 64 blocks -> 14464
    pa.tj[0]  = { P.W0, W0t_b, 1024,    0 };   // 512 tiles
    pa.tj[1]  = { P.V1, V1t_b,  512,  512 };   // 256
    pa.tj[2]  = { P.W1, W1t_b,  512,  768 };   // 256
    pa.tj[3]  = { P.V2, V2t_b,  256, 1024 };   // 128 -> 1152
    k_prep<<<dim3(15616), dim3(256), 0, stream>>>(pa);

    BW2Args ba;
    ba.Eg0b = Eg0_b; ba.W0tb = W0t_b; ba.Ed1b = Ed1_b; ba.V1tb = V1t_b;
    ba.Eg1b = Eg1_b; ba.W1tb = W1t_b; ba.Ed2b = Ed2_b; ba.V2tb = V2t_b;
    ba.Bw1b = Bw1_b; ba.Bw2b = Bw2_b;
    k_bw2<<<dim3(32), dim3(256), 0, stream>>>(ba);

    MArgsF ma;
    ma.j[0].A[0] = s2_b;  ma.j[0].B[0] = W1_b;  ma.j[0].K[0] = 512;
    ma.j[0].A[1] = xin_b; ma.j[0].B[1] = P1_b;  ma.j[0].K[1] = 1024;
    ma.j[0].A[2] = x2_b;  ma.j[0].B[2] = Ed1_b; ma.j[0].K[2] = 512;
    ma.j[0].A[3] = s1_b;  ma.j[0].B[3] = Bw1_b; ma.j[0].K[3] = 512;
    ma.j[0].jin = P.j1; ma.j[0].vin = P.v1; ma.j[0].xin = P.x1; ma.j[0].obase = 0;
    ma.j[1].A[0] = y_b;   ma.j[1].B[0] = P2_b;  ma.j[1].K[0] = 256;
    ma.j[1].A[1] = s1_b;  ma.j[1].B[1] = V1_b;  ma.j[1].K[1] = 512;
    ma.j[1].A[2] = x1_b;  ma.j[1].B[2] = Eg1_b; ma.j[1].K[2] = 512;
    ma.j[1].A[3] = s2_b;  ma.j[1].B[3] = Bw2_b; ma.j[1].K[3] = 512;
    ma.j[1].jin = P.j2; ma.j[1].vin = P.v2; ma.j[1].xin = P.x2; ma.j[1].obase = 2048;
    k_main_fast<<<dim3(512), dim3(256), 0, stream>>>(ma, out);
  } else {
    k_bw_fb<<<dim3(32), dim3(256), 0, stream>>>(P, out);
    k_main_fb<<<dim3(512), dim3(256), 0, stream>>>(P, out, 0);
    k_main_fb<<<dim3(8), dim3(256), 0, stream>>>(P, out, 1);
  }
}